// Round 1
// baseline (419.920 us; speedup 1.0000x reference)
//
#include <hip/hip_runtime.h>
#include <stdint.h>
#include <math.h>

#define HW   4096
#define NB   8
#define NC   512
#define C2   256
#define PT   32     // p-tile per block in argmax kernel

// ---------- ws layout (bytes) ----------
#define WS_PACKED 0         // u64 packed[8*4096]            = 262144
#define WS_INVN   262144    // f32 invn[8*4096]              = 131072
#define WS_Q0     393216    // i32 q0list[4096]              = 16384
#define WS_P1     409600    // i32 p1list[4096]              = 16384
#define WS_CNT    425984    // i32 cnt[2]
#define WS_IDX    427008    // i32 idx[8*4096]               = 131072
// total ~545 KB

__device__ __forceinline__ unsigned long long mkkey(float v, unsigned q) {
    unsigned u = __float_as_uint(v);
    u = (u & 0x80000000u) ? ~u : (u | 0x80000000u);   // monotone float -> u32
    return ((unsigned long long)u << 32) | (unsigned long long)(0xFFFFFFFFu - q);
}

// --- 1. deterministic sorted compaction of flag into p1 (flag==1) / q0 (flag==0)
__global__ void compact_kernel(const int* __restrict__ flag, int* __restrict__ q0,
                               int* __restrict__ p1, int* __restrict__ cnt) {
    __shared__ int c1s[256];
    int t = threadIdx.x;
    int f[16]; int n1 = 0;
    #pragma unroll
    for (int j = 0; j < 16; ++j) { f[j] = flag[t*16 + j]; n1 += (f[j] == 1); }
    c1s[t] = n1;
    __syncthreads();
    if (t == 0) {
        int run = 0;
        for (int i = 0; i < 256; ++i) { int v = c1s[i]; c1s[i] = run; run += v; }
        cnt[0] = run;          // n1
        cnt[1] = HW - run;     // n0
    }
    __syncthreads();
    int b1 = c1s[t];
    int b0 = t*16 - c1s[t];
    for (int j = 0; j < 16; ++j) {
        int i = t*16 + j;
        if (f[j] == 1) p1[b1++] = i; else q0[b0++] = i;
    }
}

// --- 2. inv norms of latter columns
__global__ void norm_kernel(const float* __restrict__ x, float* __restrict__ invn) {
    int b = blockIdx.y;
    int q = blockIdx.x * 256 + threadIdx.x;
    const float* lf = x + ((size_t)b * NC + C2) * HW + q;
    float s = 0.f;
    #pragma unroll 8
    for (int c = 0; c < C2; ++c) {
        float v = lf[c * HW];
        s = fmaf(v, v, s);
    }
    invn[b * HW + q] = 1.0f / fmaxf(sqrtf(s), 1e-8f);
}

// --- 3. cos + argmax over unmasked q, merged via packed atomicMax
__global__ void __launch_bounds__(256) argmax_kernel(
        const float* __restrict__ x, const float* __restrict__ invn,
        const int* __restrict__ q0, const int* __restrict__ p1,
        const int* __restrict__ cnt, unsigned long long* __restrict__ packed) {
    int tile  = blockIdx.x;
    int chunk = blockIdx.y;
    int b     = blockIdx.z;
    int n1 = cnt[0], n0 = cnt[1];
    if (tile * PT >= n1) return;

    __shared__ float sff[256][PT];   // ff tile: [c][p] 32 KB
    __shared__ int   sp[PT];

    int t = threadIdx.x;
    if (t < PT) sp[t] = (tile * PT + t < n1) ? p1[tile * PT + t] : -1;
    __syncthreads();

    const float* xb = x + (size_t)b * NC * HW;
    for (int i = t; i < 256 * PT; i += 256) {
        int c = i >> 5, j = i & (PT - 1);
        int p = sp[j];
        sff[c][j] = (p >= 0) ? xb[c * HW + p] : 0.f;
    }
    __syncthreads();

    int tp = t >> 6;   // 0..3  -> p sub-tile (8 p's)
    int tq = t & 63;   // lane  -> q
    const float* lfb = xb + C2 * HW;

    int half  = (n0 + 1) >> 1;
    int npass = (half + 511) >> 9;
    int qlo   = chunk * half;

    float best[8];
    int   bq[8];
    #pragma unroll
    for (int pi = 0; pi < 8; ++pi) { best[pi] = -INFINITY; bq[pi] = 0x7FFFFFFF; }

    for (int pass = 0; pass < npass; ++pass) {
        int qi0 = qlo + (pass << 9) + tq;
        int qj[8];
        #pragma unroll
        for (int j = 0; j < 8; ++j) {
            int qi = qi0 + (j << 6);
            qj[j] = (qi < n0) ? q0[qi] : 0;
        }
        float acc[8][8];
        #pragma unroll
        for (int pi = 0; pi < 8; ++pi)
            #pragma unroll
            for (int j = 0; j < 8; ++j) acc[pi][j] = 0.f;

        const float* row = lfb;
        #pragma unroll 2
        for (int c = 0; c < 256; ++c) {
            float bv[8];
            #pragma unroll
            for (int j = 0; j < 8; ++j) bv[j] = row[qj[j]];
            const float4* arow = (const float4*)&sff[c][tp * 8];
            float4 a0 = arow[0], a1 = arow[1];
            float av[8] = {a0.x, a0.y, a0.z, a0.w, a1.x, a1.y, a1.z, a1.w};
            #pragma unroll
            for (int pi = 0; pi < 8; ++pi)
                #pragma unroll
                for (int j = 0; j < 8; ++j)
                    acc[pi][j] = fmaf(av[pi], bv[j], acc[pi][j]);
            row += HW;
        }
        #pragma unroll
        for (int j = 0; j < 8; ++j) {
            int qi = qi0 + (j << 6);
            if (qi >= n0) continue;
            float sc = invn[b * HW + qj[j]];
            #pragma unroll
            for (int pi = 0; pi < 8; ++pi) {
                float cv = acc[pi][j] * sc;
                if (cv > best[pi] || (cv == best[pi] && qj[j] < bq[pi])) {
                    best[pi] = cv; bq[pi] = qj[j];
                }
            }
        }
    }

    // wave reduce (all 64 lanes share the same 8 p's)
    #pragma unroll
    for (int m = 1; m < 64; m <<= 1) {
        #pragma unroll
        for (int pi = 0; pi < 8; ++pi) {
            float ov = __shfl_xor(best[pi], m);
            int   oq = __shfl_xor(bq[pi], m);
            if (ov > best[pi] || (ov == best[pi] && oq < bq[pi])) {
                best[pi] = ov; bq[pi] = oq;
            }
        }
    }
    if (tq == 0) {
        #pragma unroll
        for (int pi = 0; pi < 8; ++pi) {
            int p = sp[tp * 8 + pi];
            if (p >= 0)
                atomicMax(&packed[(size_t)b * HW + p], mkkey(best[pi], (unsigned)bq[pi]));
        }
    }
}

// --- 4. decode packed keys -> idx
__global__ void decode_kernel(const unsigned long long* __restrict__ packed,
                              const int* __restrict__ flag, int* __restrict__ idx) {
    int b = blockIdx.y, p = blockIdx.x * 256 + threadIdx.x;
    int q = 0;
    if (flag[p] == 1) {
        unsigned low = (unsigned)(packed[(size_t)b * HW + p] & 0xFFFFFFFFull);
        q = (int)((0xFFFFFFFFu - low) & (HW - 1));
    }
    idx[b * HW + p] = q;
}

// --- 5. copy former+latter -> out channels [0,512)
__global__ void copy_kernel(const float4* __restrict__ x4, float4* __restrict__ out4) {
    size_t i = (size_t)blockIdx.x * 256 + threadIdx.x;
    if (i >= (size_t)NB * NC * (HW / 4)) return;
    size_t p4 = i & 1023;
    size_t c  = (i >> 10) & 511;
    size_t b  = i >> 19;
    out4[(b * 768 + c) * 1024 + p4] = x4[i];
}

// --- 6. shift writeback: out[b, 512+c, p] = flag[p] ? lf[b, c, idx[b,p]] : 0
__global__ void shift_kernel(const float* __restrict__ x, const int* __restrict__ flag,
                             const int* __restrict__ idx, float* __restrict__ out) {
    int cc = blockIdx.x, b = blockIdx.y;
    const float* lfrow = x + ((size_t)b * NC + C2 + cc) * HW;
    float*       orow  = out + ((size_t)b * 768 + 512 + cc) * HW;
    const int*   idxb  = idx + b * HW;
    for (int p = threadIdx.x; p < HW; p += 256) {
        float v = 0.f;
        if (flag[p] == 1) v = lfrow[idxb[p]];
        orow[p] = v;
    }
}

extern "C" void kernel_launch(void* const* d_in, const int* in_sizes, int n_in,
                              void* d_out, int out_size, void* d_ws, size_t ws_size,
                              hipStream_t stream) {
    const float* x    = (const float*)d_in[0];
    const int*   flag = (const int*)d_in[1];
    float*       out  = (float*)d_out;
    char*        ws   = (char*)d_ws;

    unsigned long long* packed = (unsigned long long*)(ws + WS_PACKED);
    float* invn = (float*)(ws + WS_INVN);
    int*   q0   = (int*)(ws + WS_Q0);
    int*   p1   = (int*)(ws + WS_P1);
    int*   cnt  = (int*)(ws + WS_CNT);
    int*   idx  = (int*)(ws + WS_IDX);

    hipMemsetAsync(packed, 0, (size_t)NB * HW * sizeof(unsigned long long), stream);

    compact_kernel<<<1, 256, 0, stream>>>(flag, q0, p1, cnt);
    norm_kernel<<<dim3(HW / 256, NB), 256, 0, stream>>>(x, invn);
    copy_kernel<<<(NB * NC * (HW / 4) + 255) / 256, 256, 0, stream>>>((const float4*)x, (float4*)out);
    argmax_kernel<<<dim3(HW / PT, 2, NB), 256, 0, stream>>>(x, invn, q0, p1, cnt, packed);
    decode_kernel<<<dim3(HW / 256, NB), 256, 0, stream>>>(packed, flag, idx);
    shift_kernel<<<dim3(C2, NB), 256, 0, stream>>>(x, flag, idx, out);
}